// Round 2
// baseline (229.134 us; speedup 1.0000x reference)
//
#include <hip/hip_runtime.h>
#include <math.h>

#define NVIEW 8
#define CIN   32
#define HF    128
#define WF    128
#define C1    32
#define C2    16
#define C3    8
#define RESO  64

// ---- shared helpers (identical expression in k_msum and k_main so masks agree) ----

static __device__ __forceinline__ float vox_coord(int idx, float b) {
    const float VOXEL = (float)(0.3 / 64.0);
    const float HALFV = (float)(0.3 / 128.0);
    return (float)idx * VOXEL + HALFV + b;
}

// mats rows 0/1 are pre-scaled by 63.5/img_w, 63.5/img_h so ix,iy come straight out.
static __device__ __forceinline__ void proj_ixiy(const float* M, float x, float y, float z,
                                                 float& ix, float& iy, float& zc) {
    float u  = fmaf(M[0], x, fmaf(M[1], y, fmaf(M[2],  z, M[3])));
    float vv = fmaf(M[4], x, fmaf(M[5], y, fmaf(M[6],  z, M[7])));
    zc       = fmaf(M[8], x, fmaf(M[9], y, fmaf(M[10], z, M[11])));
    float invz = __builtin_amdgcn_rcpf(zc);
    ix = u * invz;
    iy = vv * invz;
}

// ---- K0: mats[v] = scale_rows( Ks[v] (3x3) @ ref_poses[v] (3x4) ) ----
__global__ void k_mats(const float* __restrict__ Ks, const float* __restrict__ poses,
                       const int* __restrict__ ihp, const int* __restrict__ iwp,
                       float* __restrict__ mats) {
    int t = threadIdx.x;
    if (t < NVIEW * 12) {
        int v = t / 12, rc = t % 12, r = rc / 4, c = rc % 4;
        const float* K = Ks + v * 9;
        const float* P = poses + v * 12;
        float s = K[r*3+0]*P[0*4+c] + K[r*3+1]*P[1*4+c] + K[r*3+2]*P[2*4+c];
        float sc = (r == 0) ? 63.5f / (float)iwp[0]
                 : (r == 1) ? 63.5f / (float)ihp[0] : 1.0f;
        mats[v*12 + r*4 + c] = s * sc;
    }
}

// ---- K1: G[v][y][x][j] = b1[j] + sum_c feats[v][c][y][x] * W1[c][j]  (NHWC) ----
// LDS transpose (pad 33 -> 2 lanes/bank, free) so global stores are fully coalesced.
__global__ void __launch_bounds__(256) k_g(const float* __restrict__ feats,
                                           const float* __restrict__ W1,
                                           const float* __restrict__ b1,
                                           float* __restrict__ G) {
    __shared__ float sg[256 * 33];
    int tid = threadIdx.x;
    int t = blockIdx.x * 256 + tid;    // NVIEW*HF*WF = 131072 threads
    int x = t % WF;
    int y = (t / WF) % HF;
    int v = t / (WF * HF);
    const float* fp = feats + ((size_t)(v * CIN) * HF + y) * WF + x;
    float f[CIN];
#pragma unroll
    for (int c = 0; c < CIN; c++) f[c] = fp[(size_t)c * HF * WF];
    float g[C1];
#pragma unroll
    for (int jj = 0; jj < C1; jj++) g[jj] = b1[jj];
#pragma unroll
    for (int c = 0; c < CIN; c++) {
        float fc = f[c];
#pragma unroll
        for (int jj = 0; jj < C1; jj++) g[jj] = fmaf(fc, W1[c*C1 + jj], g[jj]);
    }
#pragma unroll
    for (int jj = 0; jj < C1; jj++) sg[tid * 33 + jj] = g[jj];
    __syncthreads();
    float* Gb = G + (size_t)blockIdx.x * (256 * C1);
#pragma unroll
    for (int q = 0; q < 32; q++) {
        int idx = q * 256 + tid;             // 0..8191, lane-consecutive
        int pp = idx >> 5, cc = idx & 31;
        Gb[idx] = sg[pp * 33 + cc];
    }
}

// ---- K2: msum[v][j][k] = sum_i mask(v, i, j, k) ----
__global__ void __launch_bounds__(128) k_msum(const float* __restrict__ mats,
                                              const float* __restrict__ bbox,
                                              float* __restrict__ msum) {
    int t = blockIdx.x * 128 + threadIdx.x;    // NVIEW*64*64 = 32768
    int k = t & 63;
    int j = (t >> 6) & 63;
    int v = t >> 12;
    float y = vox_coord(j, bbox[1]);
    float z = vox_coord(k, bbox[2]);
    const float* M = mats + v * 12;
    float s = 0.0f;
    for (int i = 0; i < RESO; i++) {
        float x = vox_coord(i, bbox[0]);
        float ix, iy, zc;
        proj_ixiy(M, x, y, z, ix, iy, zc);
        bool inb = (ix >= 0.0f) && (ix <= (float)(WF-1)) &&
                   (iy >= 0.0f) && (iy <= (float)(HF-1)) && (zc > 0.0f);
        s += inb ? 1.0f : 0.0f;
    }
    msum[t] = s;
}

// ---- K3: one thread per (voxel, view); butterfly-reduce moments over 8 lanes ----
__global__ void __launch_bounds__(256) k_main(
    const float* __restrict__ G, const float* __restrict__ msum,
    const float* __restrict__ mats, const float* __restrict__ bbox,
    const float* __restrict__ W2, const float* __restrict__ b2,
    const float* __restrict__ W3, const float* __restrict__ b3,
    float* __restrict__ out) {
    int t = blockIdx.x * 256 + threadIdx.x;    // 2,097,152 threads
    int v = t & 7;
    int p = t >> 3;                            // voxel: i fastest
    int i = p & 63;
    int j = (p >> 6) & 63;
    int k = p >> 12;
    float x = vox_coord(i, bbox[0]);
    float y = vox_coord(j, bbox[1]);
    float z = vox_coord(k, bbox[2]);

    const float* M = mats + v * 12;
    float ix, iy, zc;
    proj_ixiy(M, x, y, z, ix, iy, zc);

    float fx0 = floorf(ix), fy0 = floorf(iy);
    float fx1 = fx0 + 1.0f, fy1 = fy0 + 1.0f;
    bool inb = (ix >= 0.0f) && (ix <= (float)(WF-1)) &&
               (iy >= 0.0f) && (iy <= (float)(HF-1)) && (zc > 0.0f);
    int cx0 = (int)fminf(fmaxf(fx0, 0.0f), (float)(WF-1));
    int cx1 = (int)fminf(fmaxf(fx1, 0.0f), (float)(WF-1));
    int cy0 = (int)fminf(fmaxf(fy0, 0.0f), (float)(HF-1));
    int cy1 = (int)fminf(fmaxf(fy1, 0.0f), (float)(HF-1));
    float wnw = (fx1 - ix) * (fy1 - iy);
    float wne = (ix - fx0) * (fy1 - iy);
    float wsw = (fx1 - ix) * (iy - fy0);
    float wse = (ix - fx0) * (iy - fy0);

    const float4* Gv  = (const float4*)(G + (size_t)v * HF * WF * C1);
    const float4* pnw = Gv + (size_t)(cy0 * WF + cx0) * (C1/4);
    const float4* pne = Gv + (size_t)(cy0 * WF + cx1) * (C1/4);
    const float4* psw = Gv + (size_t)(cy1 * WF + cx0) * (C1/4);
    const float4* pse = Gv + (size_t)(cy1 * WF + cx1) * (C1/4);

    float h1[C1];
#pragma unroll
    for (int q = 0; q < C1/4; q++) {
        float4 a = pnw[q], b = pne[q], c4 = psw[q], d = pse[q];
        h1[4*q+0] = fmaxf(fmaf(wnw, a.x, fmaf(wne, b.x, fmaf(wsw, c4.x, wse * d.x))), 0.0f);
        h1[4*q+1] = fmaxf(fmaf(wnw, a.y, fmaf(wne, b.y, fmaf(wsw, c4.y, wse * d.y))), 0.0f);
        h1[4*q+2] = fmaxf(fmaf(wnw, a.z, fmaf(wne, b.z, fmaf(wsw, c4.z, wse * d.z))), 0.0f);
        h1[4*q+3] = fmaxf(fmaf(wnw, a.w, fmaf(wne, b.w, fmaf(wsw, c4.w, wse * d.w))), 0.0f);
    }

    float h2[C2];
#pragma unroll
    for (int o = 0; o < C2; o++) h2[o] = b2[o];
#pragma unroll
    for (int jj = 0; jj < C1; jj++) {
        float hv = h1[jj];
#pragma unroll
        for (int o = 0; o < C2; o++) h2[o] = fmaf(hv, W2[jj*C2 + o], h2[o]);
    }
#pragma unroll
    for (int o = 0; o < C2; o++) h2[o] = fmaxf(h2[o], 0.0f);

    float cp[C3];
#pragma unroll
    for (int c = 0; c < C3; c++) cp[c] = b3[c];
#pragma unroll
    for (int o = 0; o < C2; o++) {
        float hv = h2[o];
#pragma unroll
        for (int c = 0; c < C3; c++) cp[c] = fmaf(hv, W3[o*C3 + c], cp[c]);
    }

    float ms = msum[(v << 12) | (j << 6) | k];
    float w = inb ? __builtin_amdgcn_rcpf(ms + 1e-8f) : 0.0f;

    float S = w;
    float a1[C3], a2[C3];
#pragma unroll
    for (int c = 0; c < C3; c++) {
        a1[c] = w * cp[c];
        a2[c] = w * cp[c] * cp[c];
    }

    // butterfly over lane bits 0..2 (the 8 views of this voxel)
#pragma unroll
    for (int m = 1; m <= 4; m <<= 1) {
        S += __shfl_xor(S, m);
#pragma unroll
        for (int c = 0; c < C3; c++) {
            a1[c] += __shfl_xor(a1[c], m);
            a2[c] += __shfl_xor(a2[c], m);
        }
    }

    // lane with local view v writes mean plane v and var plane v+8
    float mv = 0.0f, qv = 0.0f;
#pragma unroll
    for (int c = 0; c < C3; c++) {
        if (v == c) { mv = a1[c]; qv = a2[c]; }
    }
    out[(size_t)v * 262144 + p]       = mv;
    out[(size_t)(v + 8) * 262144 + p] = fmaf(mv * mv, S - 2.0f, qv);
}

// ---- launch ----
extern "C" void kernel_launch(void* const* d_in, const int* in_sizes, int n_in,
                              void* d_out, int out_size, void* d_ws, size_t ws_size,
                              hipStream_t stream) {
    const float* feats = (const float*)d_in[0];
    const float* poses = (const float*)d_in[1];
    const float* Ks    = (const float*)d_in[2];
    const float* bbox  = (const float*)d_in[3];
    const int*   img_h = (const int*)d_in[4];
    const int*   img_w = (const int*)d_in[5];
    const float* W1    = (const float*)d_in[6];
    const float* b1    = (const float*)d_in[7];
    const float* W2    = (const float*)d_in[8];
    const float* b2    = (const float*)d_in[9];
    const float* W3    = (const float*)d_in[10];
    const float* b3    = (const float*)d_in[11];
    float* out = (float*)d_out;
    float* ws  = (float*)d_ws;

    float* mats = ws;           // 96 floats
    float* msum = ws + 128;     // 32768 floats
    float* G    = ws + 33024;   // 8*128*128*32 = 4,194,304 floats (16 MB), 16B-aligned

    hipLaunchKernelGGL(k_mats, dim3(1),    dim3(128), 0, stream, Ks, poses, img_h, img_w, mats);
    hipLaunchKernelGGL(k_g,    dim3(512),  dim3(256), 0, stream, feats, W1, b1, G);
    hipLaunchKernelGGL(k_msum, dim3(256),  dim3(128), 0, stream, mats, bbox, msum);
    hipLaunchKernelGGL(k_main, dim3(8192), dim3(256), 0, stream,
                       G, msum, mats, bbox, W2, b2, W3, b3, out);
}

// Round 3
// 213.949 us; speedup vs baseline: 1.0710x; 1.0710x over previous
//
#include <hip/hip_runtime.h>
#include <math.h>

#define NVIEW 8
#define CIN   32
#define HF    128
#define WF    128
#define C1    32
#define C2    16
#define C3    8
#define RESO  64
#define PLANE (HF*WF)          // 16384 texels per (v,q) plane, float4 units

// ---- shared helpers (identical expression in k_msum and k_main so masks agree) ----

static __device__ __forceinline__ float vox_coord(int idx, float b) {
    const float VOXEL = (float)(0.3 / 64.0);
    const float HALFV = (float)(0.3 / 128.0);
    return (float)idx * VOXEL + HALFV + b;
}

// mats rows 0/1 are pre-scaled by 63.5/img_w, 63.5/img_h so ix,iy come straight out.
static __device__ __forceinline__ void proj_ixiy(const float* M, float x, float y, float z,
                                                 float& ix, float& iy, float& zc) {
    float u  = fmaf(M[0], x, fmaf(M[1], y, fmaf(M[2],  z, M[3])));
    float vv = fmaf(M[4], x, fmaf(M[5], y, fmaf(M[6],  z, M[7])));
    zc       = fmaf(M[8], x, fmaf(M[9], y, fmaf(M[10], z, M[11])));
    float invz = __builtin_amdgcn_rcpf(zc);
    ix = u * invz;
    iy = vv * invz;
}

// ---- K0: mats[v] = scale_rows( Ks[v] (3x3) @ ref_poses[v] (3x4) ) ----
__global__ void k_mats(const float* __restrict__ Ks, const float* __restrict__ poses,
                       const int* __restrict__ ihp, const int* __restrict__ iwp,
                       float* __restrict__ mats) {
    int t = threadIdx.x;
    if (t < NVIEW * 12) {
        int v = t / 12, rc = t % 12, r = rc / 4, c = rc % 4;
        const float* K = Ks + v * 9;
        const float* P = poses + v * 12;
        float s = K[r*3+0]*P[0*4+c] + K[r*3+1]*P[1*4+c] + K[r*3+2]*P[2*4+c];
        float sc = (r == 0) ? 63.5f / (float)iwp[0]
                 : (r == 1) ? 63.5f / (float)ihp[0] : 1.0f;
        mats[v*12 + r*4 + c] = s * sc;
    }
}

// ---- K1: G planar-quad layout: G4[(v*8+q)*PLANE + y*W+x] = quad q of (b1 + feats@W1) ----
// Loads coalesced per input channel; stores coalesced per plane. No LDS needed.
__global__ void __launch_bounds__(256) k_g(const float* __restrict__ feats,
                                           const float* __restrict__ W1,
                                           const float* __restrict__ b1,
                                           float4* __restrict__ G4) {
    int t = blockIdx.x * 256 + threadIdx.x;    // NVIEW*HF*WF = 131072 threads
    int pix = t & (PLANE - 1);                 // y*128 + x
    int v = t >> 14;
    const float* fp = feats + ((size_t)v * CIN) * PLANE + pix;
    float f[CIN];
#pragma unroll
    for (int c = 0; c < CIN; c++) f[c] = fp[(size_t)c * PLANE];
    float g[C1];
#pragma unroll
    for (int jj = 0; jj < C1; jj++) g[jj] = b1[jj];
#pragma unroll
    for (int c = 0; c < CIN; c++) {
        float fc = f[c];
#pragma unroll
        for (int jj = 0; jj < C1; jj++) g[jj] = fmaf(fc, W1[c*C1 + jj], g[jj]);
    }
#pragma unroll
    for (int q = 0; q < C1/4; q++)
        G4[((size_t)(v * 8 + q)) * PLANE + pix] =
            make_float4(g[4*q], g[4*q+1], g[4*q+2], g[4*q+3]);
}

// ---- K2: msum[v][j][k] = sum_i mask(v, i, j, k) ----
__global__ void __launch_bounds__(128) k_msum(const float* __restrict__ mats,
                                              const float* __restrict__ bbox,
                                              float* __restrict__ msum) {
    int t = blockIdx.x * 128 + threadIdx.x;    // NVIEW*64*64 = 32768
    int k = t & 63;
    int j = (t >> 6) & 63;
    int v = t >> 12;
    float y = vox_coord(j, bbox[1]);
    float z = vox_coord(k, bbox[2]);
    const float* M = mats + v * 12;
    float s = 0.0f;
    for (int i = 0; i < RESO; i++) {
        float x = vox_coord(i, bbox[0]);
        float ix, iy, zc;
        proj_ixiy(M, x, y, z, ix, iy, zc);
        bool inb = (ix >= 0.0f) && (ix <= (float)(WF-1)) &&
                   (iy >= 0.0f) && (iy <= (float)(HF-1)) && (zc > 0.0f);
        s += inb ? 1.0f : 0.0f;
    }
    msum[t] = s;
}

// ---- K3: thread = voxel; serial 8-view loop; planar-quad gathers ----
__global__ void __launch_bounds__(256) k_main(
    const float4* __restrict__ G4, const float* __restrict__ msum,
    const float* __restrict__ mats, const float* __restrict__ bbox,
    const float* __restrict__ W2, const float* __restrict__ b2,
    const float* __restrict__ W3, const float* __restrict__ b3,
    float* __restrict__ out) {
    int t = blockIdx.x * 256 + threadIdx.x;    // 262144 threads; i fastest (coalesced)
    int i = t & 63;
    int j = (t >> 6) & 63;
    int k = t >> 12;
    float x = vox_coord(i, bbox[0]);
    float y = vox_coord(j, bbox[1]);
    float z = vox_coord(k, bbox[2]);

    float M1[C3], Msq[C3];
    float S = 0.0f;
#pragma unroll
    for (int c = 0; c < C3; c++) { M1[c] = 0.0f; Msq[c] = 0.0f; }

#pragma unroll 1
    for (int v = 0; v < NVIEW; v++) {
        const float* M = mats + v * 12;
        float ix, iy, zc;
        proj_ixiy(M, x, y, z, ix, iy, zc);

        float fx0 = floorf(ix), fy0 = floorf(iy);
        float fx1 = fx0 + 1.0f, fy1 = fy0 + 1.0f;
        bool inb = (ix >= 0.0f) && (ix <= (float)(WF-1)) &&
                   (iy >= 0.0f) && (iy <= (float)(HF-1)) && (zc > 0.0f);
        int cx0 = (int)fminf(fmaxf(fx0, 0.0f), (float)(WF-1));
        int cx1 = (int)fminf(fmaxf(fx1, 0.0f), (float)(WF-1));
        int cy0 = (int)fminf(fmaxf(fy0, 0.0f), (float)(HF-1));
        int cy1 = (int)fminf(fmaxf(fy1, 0.0f), (float)(HF-1));
        float wnw = (fx1 - ix) * (fy1 - iy);
        float wne = (ix - fx0) * (fy1 - iy);
        float wsw = (fx1 - ix) * (iy - fy0);
        float wse = (ix - fx0) * (iy - fy0);

        int t00 = cy0 * WF + cx0, t01 = cy0 * WF + cx1;
        int t10 = cy1 * WF + cx0, t11 = cy1 * WF + cx1;
        const float4* Gv = G4 + (size_t)v * 8 * PLANE;

        float h1[C1];
#pragma unroll
        for (int q = 0; q < C1/4; q++) {
            const float4* P = Gv + q * PLANE;
            float4 a = P[t00], b = P[t01], c4 = P[t10], d = P[t11];
            h1[4*q+0] = fmaxf(fmaf(wnw, a.x, fmaf(wne, b.x, fmaf(wsw, c4.x, wse * d.x))), 0.0f);
            h1[4*q+1] = fmaxf(fmaf(wnw, a.y, fmaf(wne, b.y, fmaf(wsw, c4.y, wse * d.y))), 0.0f);
            h1[4*q+2] = fmaxf(fmaf(wnw, a.z, fmaf(wne, b.z, fmaf(wsw, c4.z, wse * d.z))), 0.0f);
            h1[4*q+3] = fmaxf(fmaf(wnw, a.w, fmaf(wne, b.w, fmaf(wsw, c4.w, wse * d.w))), 0.0f);
        }

        float h2[C2];
#pragma unroll
        for (int o = 0; o < C2; o++) h2[o] = b2[o];
#pragma unroll
        for (int jj = 0; jj < C1; jj++) {
            float hv = h1[jj];
#pragma unroll
            for (int o = 0; o < C2; o++) h2[o] = fmaf(hv, W2[jj*C2 + o], h2[o]);
        }
#pragma unroll
        for (int o = 0; o < C2; o++) h2[o] = fmaxf(h2[o], 0.0f);

        float cp[C3];
#pragma unroll
        for (int c = 0; c < C3; c++) cp[c] = b3[c];
#pragma unroll
        for (int o = 0; o < C2; o++) {
            float hv = h2[o];
#pragma unroll
            for (int c = 0; c < C3; c++) cp[c] = fmaf(hv, W3[o*C3 + c], cp[c]);
        }

        float ms = msum[(v << 12) | (j << 6) | k];
        float w = inb ? __builtin_amdgcn_rcpf(ms + 1e-8f) : 0.0f;
        S += w;
#pragma unroll
        for (int c = 0; c < C3; c++) {
            M1[c]  = fmaf(w, cp[c], M1[c]);
            Msq[c] = fmaf(w * cp[c], cp[c], Msq[c]);
        }
    }

    // out[0][ch][k][j][i]: ch 0..7 = mean, 8..15 = var = M2 + mean^2*(S-2)
    size_t ob = (size_t)k * 4096 + (size_t)j * 64 + (size_t)i;
#pragma unroll
    for (int c = 0; c < C3; c++) {
        out[(size_t)c * 262144 + ob] = M1[c];
        out[(size_t)(c + 8) * 262144 + ob] = fmaf(M1[c] * M1[c], S - 2.0f, Msq[c]);
    }
}

// ---- launch ----
extern "C" void kernel_launch(void* const* d_in, const int* in_sizes, int n_in,
                              void* d_out, int out_size, void* d_ws, size_t ws_size,
                              hipStream_t stream) {
    const float* feats = (const float*)d_in[0];
    const float* poses = (const float*)d_in[1];
    const float* Ks    = (const float*)d_in[2];
    const float* bbox  = (const float*)d_in[3];
    const int*   img_h = (const int*)d_in[4];
    const int*   img_w = (const int*)d_in[5];
    const float* W1    = (const float*)d_in[6];
    const float* b1    = (const float*)d_in[7];
    const float* W2    = (const float*)d_in[8];
    const float* b2    = (const float*)d_in[9];
    const float* W3    = (const float*)d_in[10];
    const float* b3    = (const float*)d_in[11];
    float* out = (float*)d_out;
    float* ws  = (float*)d_ws;

    float*  mats = ws;           // 96 floats
    float*  msum = ws + 128;     // 32768 floats
    float4* G4   = (float4*)(ws + 33024);   // 8*8*16384 float4 = 16 MB, 16B-aligned

    hipLaunchKernelGGL(k_mats, dim3(1),    dim3(128), 0, stream, Ks, poses, img_h, img_w, mats);
    hipLaunchKernelGGL(k_g,    dim3(512),  dim3(256), 0, stream, feats, W1, b1, G4);
    hipLaunchKernelGGL(k_msum, dim3(256),  dim3(128), 0, stream, mats, bbox, msum);
    hipLaunchKernelGGL(k_main, dim3(1024), dim3(256), 0, stream,
                       G4, msum, mats, bbox, W2, b2, W3, b3, out);
}

// Round 5
// 166.767 us; speedup vs baseline: 1.3740x; 1.2829x over previous
//
#include <hip/hip_runtime.h>
#include <math.h>

#define NVIEW 8
#define CIN   32
#define HF    128
#define WF    128
#define C1    32
#define C2    16
#define C3    8
#define RESO  64
#define PLANE (HF*WF)          // 16384 texels per (v,q) plane, float4 units

typedef _Float16 half8_t  __attribute__((ext_vector_type(8)));
typedef _Float16 half2_t  __attribute__((ext_vector_type(2)));
typedef float    floatx4  __attribute__((ext_vector_type(4)));

// ---- shared helpers (identical expression in k_msum and k_main so masks agree) ----

static __device__ __forceinline__ float vox_coord(int idx, float b) {
    const float VOXEL = (float)(0.3 / 64.0);
    const float HALFV = (float)(0.3 / 128.0);
    return (float)idx * VOXEL + HALFV + b;
}

// mats rows 0/1 pre-scaled by 63.5/img_w, 63.5/img_h so ix,iy come straight out.
static __device__ __forceinline__ void proj_ixiy(const float* M, float x, float y, float z,
                                                 float& ix, float& iy, float& zc) {
    float u  = fmaf(M[0], x, fmaf(M[1], y, fmaf(M[2],  z, M[3])));
    float vv = fmaf(M[4], x, fmaf(M[5], y, fmaf(M[6],  z, M[7])));
    zc       = fmaf(M[8], x, fmaf(M[9], y, fmaf(M[10], z, M[11])));
    float invz = __builtin_amdgcn_rcpf(zc);
    ix = u * invz;
    iy = vv * invz;
}

// ---- K0: mats + fp16 weight fragments (B-layout) + bias-per-lane tables ----
__global__ void k_prep(const float* __restrict__ Ks, const float* __restrict__ poses,
                       const int* __restrict__ ihp, const int* __restrict__ iwp,
                       const float* __restrict__ W2, const float* __restrict__ b2,
                       const float* __restrict__ W3, const float* __restrict__ b3,
                       float* __restrict__ mats,
                       _Float16* __restrict__ w2f, _Float16* __restrict__ w3f,
                       float* __restrict__ b2f, float* __restrict__ b3f) {
    int t = threadIdx.x;
    if (t < NVIEW * 12) {
        int v = t / 12, rc = t % 12, r = rc / 4, c = rc % 4;
        const float* K = Ks + v * 9;
        const float* P = poses + v * 12;
        float s = K[r*3+0]*P[0*4+c] + K[r*3+1]*P[1*4+c] + K[r*3+2]*P[2*4+c];
        float sc = (r == 0) ? 63.5f / (float)iwp[0]
                 : (r == 1) ? 63.5f / (float)ihp[0] : 1.0f;
        mats[v*12 + r*4 + c] = s * sc;
    }
    if (t < 64) {
        int n = t & 15, g = t >> 4;
        // B-frag for mfma_f32_16x16x32_f16: lane holds B[k=8g+j][n], j=0..7
#pragma unroll
        for (int jj = 0; jj < 8; jj++) {
            int kk = 8 * g + jj;
            w2f[t*8 + jj] = (_Float16)W2[kk * C2 + n];
            float w3v = (kk < C2 && n < C3) ? W3[kk * C3 + n] : 0.0f;  // K,N zero-pad
            w3f[t*8 + jj] = (_Float16)w3v;
        }
        b2f[t] = b2[n];
        b3f[t] = (n < C3) ? b3[n] : 0.0f;
    }
}

// ---- K1: G planar-quad: G4[(v*8+q)*PLANE + y*W+x] = quad q of (b1 + feats@W1) ----
__global__ void __launch_bounds__(256) k_g(const float* __restrict__ feats,
                                           const float* __restrict__ W1,
                                           const float* __restrict__ b1,
                                           float4* __restrict__ G4) {
    int t = blockIdx.x * 256 + threadIdx.x;    // NVIEW*HF*WF = 131072 threads
    int pix = t & (PLANE - 1);
    int v = t >> 14;
    const float* fp = feats + ((size_t)v * CIN) * PLANE + pix;
    float f[CIN];
#pragma unroll
    for (int c = 0; c < CIN; c++) f[c] = fp[(size_t)c * PLANE];
    float g[C1];
#pragma unroll
    for (int jj = 0; jj < C1; jj++) g[jj] = b1[jj];
#pragma unroll
    for (int c = 0; c < CIN; c++) {
        float fc = f[c];
#pragma unroll
        for (int jj = 0; jj < C1; jj++) g[jj] = fmaf(fc, W1[c*C1 + jj], g[jj]);
    }
#pragma unroll
    for (int q = 0; q < C1/4; q++)
        G4[((size_t)(v * 8 + q)) * PLANE + pix] =
            make_float4(g[4*q], g[4*q+1], g[4*q+2], g[4*q+3]);
}

// ---- K2: msum[v][j][k] = sum_i mask(v, i, j, k) ----
__global__ void __launch_bounds__(128) k_msum(const float* __restrict__ mats,
                                              const float* __restrict__ bbox,
                                              float* __restrict__ msum) {
    int t = blockIdx.x * 128 + threadIdx.x;    // NVIEW*64*64 = 32768
    int k = t & 63;
    int j = (t >> 6) & 63;
    int v = t >> 12;
    float y = vox_coord(j, bbox[1]);
    float z = vox_coord(k, bbox[2]);
    const float* M = mats + v * 12;
    float s = 0.0f;
    for (int i = 0; i < RESO; i++) {
        float x = vox_coord(i, bbox[0]);
        float ix, iy, zc;
        proj_ixiy(M, x, y, z, ix, iy, zc);
        bool inb = (ix >= 0.0f) && (ix <= (float)(WF-1)) &&
                   (iy >= 0.0f) && (iy <= (float)(HF-1)) && (zc > 0.0f);
        s += inb ? 1.0f : 0.0f;
    }
    msum[t] = s;
}

// ---- K3: 1 wave per 64 voxels; layers 2+3 on MFMA; moments in C-layout ----
__global__ void __launch_bounds__(64) k_main(
    const float4* __restrict__ G4, const float* __restrict__ msum,
    const float* __restrict__ mats, const float* __restrict__ bbox,
    const _Float16* __restrict__ w2f, const _Float16* __restrict__ w3f,
    const float* __restrict__ b2f, const float* __restrict__ b3f,
    float* __restrict__ out) {
    __shared__ __align__(16) char smem[5120 + 3072 + 256];
    char*     h1lds = smem;                         // 64 pts * 80 B (32 f16 padded)
    _Float16* h2h   = (_Float16*)(smem + 5120);     // 64 pts * 48 B (16 f16 padded to 24)
    float*    wbufF = (float*)(smem + 5120 + 3072); // 64 w values

    int lane = threadIdx.x;
    int bid  = blockIdx.x;                 // 4096 blocks
    int i = lane;
    int j = bid & 63;
    int k = bid >> 6;
    float x = vox_coord(i, bbox[0]);
    float y = vox_coord(j, bbox[1]);
    float z = vox_coord(k, bbox[2]);

    int m = lane & 15, g = lane >> 4;
    half8_t w2frag = *(const half8_t*)(w2f + lane * 8);
    half8_t w3frag = *(const half8_t*)(w3f + lane * 8);
    float b2c = b2f[lane];
    float b3c = b3f[lane];
    floatx4 zf4 = {0.0f, 0.0f, 0.0f, 0.0f};

    float M1[16], Msq[16];
    float S = 0.0f;
#pragma unroll
    for (int c = 0; c < 16; c++) { M1[c] = 0.0f; Msq[c] = 0.0f; }

#pragma unroll 1
    for (int v = 0; v < NVIEW; v++) {
        const float* M = mats + v * 12;
        float ix, iy, zc;
        proj_ixiy(M, x, y, z, ix, iy, zc);

        float fx0 = floorf(ix), fy0 = floorf(iy);
        float fx1 = fx0 + 1.0f, fy1 = fy0 + 1.0f;
        bool inb = (ix >= 0.0f) && (ix <= (float)(WF-1)) &&
                   (iy >= 0.0f) && (iy <= (float)(HF-1)) && (zc > 0.0f);
        int cx0 = (int)fminf(fmaxf(fx0, 0.0f), (float)(WF-1));
        int cx1 = (int)fminf(fmaxf(fx1, 0.0f), (float)(WF-1));
        int cy0 = (int)fminf(fmaxf(fy0, 0.0f), (float)(HF-1));
        int cy1 = (int)fminf(fmaxf(fy1, 0.0f), (float)(HF-1));
        float wnw = (fx1 - ix) * (fy1 - iy);
        float wne = (ix - fx0) * (fy1 - iy);
        float wsw = (fx1 - ix) * (iy - fy0);
        float wse = (ix - fx0) * (iy - fy0);

        int t00 = cy0 * WF + cx0, t01 = cy0 * WF + cx1;
        int t10 = cy1 * WF + cx0, t11 = cy1 * WF + cx1;
        const float4* Gv = G4 + (size_t)v * 8 * PLANE;

        // blend + relu -> h1 (fp32), then pack rtz -> fp16 pairs
        half2_t hp[16];
#pragma unroll
        for (int q = 0; q < C1/4; q++) {
            const float4* P = Gv + q * PLANE;
            float4 a = P[t00], b = P[t01], c4 = P[t10], d = P[t11];
            float e0 = fmaxf(fmaf(wnw, a.x, fmaf(wne, b.x, fmaf(wsw, c4.x, wse * d.x))), 0.0f);
            float e1 = fmaxf(fmaf(wnw, a.y, fmaf(wne, b.y, fmaf(wsw, c4.y, wse * d.y))), 0.0f);
            float e2 = fmaxf(fmaf(wnw, a.z, fmaf(wne, b.z, fmaf(wsw, c4.z, wse * d.z))), 0.0f);
            float e3 = fmaxf(fmaf(wnw, a.w, fmaf(wne, b.w, fmaf(wsw, c4.w, wse * d.w))), 0.0f);
            hp[2*q+0] = __builtin_bit_cast(half2_t, __builtin_amdgcn_cvt_pkrtz(e0, e1));
            hp[2*q+1] = __builtin_bit_cast(half2_t, __builtin_amdgcn_cvt_pkrtz(e2, e3));
        }
        {
            uint4* dst = (uint4*)(h1lds + lane * 80);
            const uint4* src = (const uint4*)hp;
            dst[0] = src[0]; dst[1] = src[1]; dst[2] = src[2]; dst[3] = src[3];
        }
        __syncthreads();

        // layer 2: 4x mfma 16x16x32 f16  (A: h1 of 16 points, B: W2)
        floatx4 c2[4];
#pragma unroll
        for (int T = 0; T < 4; T++) {
            half8_t aT = *(const half8_t*)(h1lds + (size_t)(T*16 + m) * 80 + g * 16);
            c2[T] = __builtin_amdgcn_mfma_f32_16x16x32_f16(aT, w2frag, zf4, 0, 0, 0);
        }
        // bias + relu in C-layout, store h2 as fp16 [point][channel]
#pragma unroll
        for (int T = 0; T < 4; T++) {
#pragma unroll
            for (int r = 0; r < 4; r++) {
                float vv = fmaxf(c2[T][r] + b2c, 0.0f);
                h2h[(size_t)(T*16 + g*4 + r) * 24 + m] = (_Float16)vv;
            }
        }
        __syncthreads();

        // layer 3: 4x mfma 16x16x32 f16, K zero-padded via w3frag (g>=2 rows are 0)
        floatx4 c3[4];
#pragma unroll
        for (int T = 0; T < 4; T++) {
            half8_t a3 = *(const half8_t*)(h2h + (size_t)(T*16 + m) * 24 + (g & 1) * 8);
            c3[T] = __builtin_amdgcn_mfma_f32_16x16x32_f16(a3, w3frag, zf4, 0, 0, 0);
        }

        // per-point weight -> broadcast to C-layout via LDS
        float ms = msum[(v << 12) | (j << 6) | k];
        float w = inb ? __builtin_amdgcn_rcpf(ms + 1e-8f) : 0.0f;
        wbufF[lane] = w;
        S += w;
        __syncthreads();
#pragma unroll
        for (int T = 0; T < 4; T++) {
            floatx4 w4 = *(const floatx4*)(wbufF + T*16 + g*4);
#pragma unroll
            for (int r = 0; r < 4; r++) {
                float val = c3[T][r] + b3c;
                float t1 = w4[r] * val;
                M1[T*4+r]  += t1;
                Msq[T*4+r]  = fmaf(t1, val, Msq[T*4+r]);
            }
        }
        __syncthreads();   // protect h1/h2/wbuf reuse next view
    }

    // epilogue: S -> C-layout, then float4 stores per channel plane
    wbufF[lane] = S;
    __syncthreads();
    if (m < C3) {
        size_t base = (size_t)bid * 64;
#pragma unroll
        for (int T = 0; T < 4; T++) {
            floatx4 s4 = *(const floatx4*)(wbufF + T*16 + g*4);
            float4 mn, vr;
            mn.x = M1[T*4+0]; mn.y = M1[T*4+1]; mn.z = M1[T*4+2]; mn.w = M1[T*4+3];
            vr.x = fmaf(mn.x*mn.x, s4[0]-2.0f, Msq[T*4+0]);
            vr.y = fmaf(mn.y*mn.y, s4[1]-2.0f, Msq[T*4+1]);
            vr.z = fmaf(mn.z*mn.z, s4[2]-2.0f, Msq[T*4+2]);
            vr.w = fmaf(mn.w*mn.w, s4[3]-2.0f, Msq[T*4+3]);
            size_t ob = base + T*16 + g*4;
            *(float4*)(out + (size_t)m       * 262144 + ob) = mn;
            *(float4*)(out + (size_t)(m + 8) * 262144 + ob) = vr;
        }
    }
}

// ---- launch ----
extern "C" void kernel_launch(void* const* d_in, const int* in_sizes, int n_in,
                              void* d_out, int out_size, void* d_ws, size_t ws_size,
                              hipStream_t stream) {
    const float* feats = (const float*)d_in[0];
    const float* poses = (const float*)d_in[1];
    const float* Ks    = (const float*)d_in[2];
    const float* bbox  = (const float*)d_in[3];
    const int*   img_h = (const int*)d_in[4];
    const int*   img_w = (const int*)d_in[5];
    const float* W1    = (const float*)d_in[6];
    const float* b1    = (const float*)d_in[7];
    const float* W2    = (const float*)d_in[8];
    const float* b2    = (const float*)d_in[9];
    const float* W3    = (const float*)d_in[10];
    const float* b3    = (const float*)d_in[11];
    float* out = (float*)d_out;
    float* ws  = (float*)d_ws;

    float*     mats = ws;                        // 96 floats (pad to 128)
    float*     msum = ws + 128;                  // 32768 floats
    _Float16*  w2f  = (_Float16*)(ws + 32896);   // 512 halves (256 floats)
    _Float16*  w3f  = (_Float16*)(ws + 33152);   // 512 halves (256 floats)
    float*     b2f  = ws + 33408;                // 64
    float*     b3f  = ws + 33472;                // 64
    float4*    G4   = (float4*)(ws + 33536);     // 8*8*16384 float4 = 16 MB, 16B-aligned

    hipLaunchKernelGGL(k_prep, dim3(1),    dim3(128), 0, stream,
                       Ks, poses, img_h, img_w, W2, b2, W3, b3, mats, w2f, w3f, b2f, b3f);
    hipLaunchKernelGGL(k_g,    dim3(512),  dim3(256), 0, stream, feats, W1, b1, G4);
    hipLaunchKernelGGL(k_msum, dim3(256),  dim3(128), 0, stream, mats, bbox, msum);
    hipLaunchKernelGGL(k_main, dim3(4096), dim3(64),  0, stream,
                       G4, msum, mats, bbox, w2f, w3f, b2f, b3f, out);
}

// Round 6
// 141.469 us; speedup vs baseline: 1.6197x; 1.1788x over previous
//
#include <hip/hip_runtime.h>
#include <math.h>

#define NVIEW 8
#define CIN   32
#define HF    128
#define WF    128
#define C1    32
#define C2    16
#define C3    8
#define RESO  64
#define PLANE (HF*WF)          // 16384 texels per (v,q) plane, float4 units

typedef _Float16 half8_t  __attribute__((ext_vector_type(8)));
typedef _Float16 half2_t  __attribute__((ext_vector_type(2)));
typedef float    floatx4  __attribute__((ext_vector_type(4)));

static __device__ __forceinline__ float vox_coord(int idx, float b) {
    const float VOXEL = (float)(0.3 / 64.0);
    const float HALFV = (float)(0.3 / 128.0);
    return (float)idx * VOXEL + HALFV + b;
}

// mats rows 0/1 pre-scaled by 63.5/img_w, 63.5/img_h so ix,iy come straight out.
static __device__ __forceinline__ void proj_ixiy(const float* M, float x, float y, float z,
                                                 float& ix, float& iy, float& zc) {
    float u  = fmaf(M[0], x, fmaf(M[1], y, fmaf(M[2],  z, M[3])));
    float vv = fmaf(M[4], x, fmaf(M[5], y, fmaf(M[6],  z, M[7])));
    zc       = fmaf(M[8], x, fmaf(M[9], y, fmaf(M[10], z, M[11])));
    float invz = __builtin_amdgcn_rcpf(zc);
    ix = u * invz;
    iy = vv * invz;
}

// wave-level LDS sync: block == 1 wave, DS ops are in-order per wave; only need
// lgkmcnt drain + compiler barrier. No s_barrier, no vmcnt(0) drain.
static __device__ __forceinline__ void wave_lds_sync() {
    asm volatile("s_waitcnt lgkmcnt(0)" ::: "memory");
}

// ---- K1: G planar-quad + (block 512) prep of mats / fp16 weight frags ----
__global__ void __launch_bounds__(256) k_g(const float* __restrict__ feats,
                                           const float* __restrict__ W1,
                                           const float* __restrict__ b1,
                                           float4* __restrict__ G4,
                                           const float* __restrict__ Ks,
                                           const float* __restrict__ poses,
                                           const int* __restrict__ ihp,
                                           const int* __restrict__ iwp,
                                           const float* __restrict__ W2,
                                           const float* __restrict__ b2,
                                           const float* __restrict__ W3,
                                           const float* __restrict__ b3,
                                           float* __restrict__ mats,
                                           _Float16* __restrict__ w2f,
                                           _Float16* __restrict__ w3f,
                                           float* __restrict__ b2f,
                                           float* __restrict__ b3f) {
    if (blockIdx.x == 512) {
        int t = threadIdx.x;
        if (t < NVIEW * 12) {
            int v = t / 12, rc = t % 12, r = rc / 4, c = rc % 4;
            const float* K = Ks + v * 9;
            const float* P = poses + v * 12;
            float s = K[r*3+0]*P[0*4+c] + K[r*3+1]*P[1*4+c] + K[r*3+2]*P[2*4+c];
            float sc = (r == 0) ? 63.5f / (float)iwp[0]
                     : (r == 1) ? 63.5f / (float)ihp[0] : 1.0f;
            mats[v*12 + r*4 + c] = s * sc;
        }
        if (t < 64) {
            int n = t & 15, g = t >> 4;
            // B-frag for mfma_f32_16x16x32_f16: lane holds B[k=8g+j][n], j=0..7
#pragma unroll
            for (int jj = 0; jj < 8; jj++) {
                int kk = 8 * g + jj;
                w2f[t*8 + jj] = (_Float16)W2[kk * C2 + n];
                float w3v = (kk < C2 && n < C3) ? W3[kk * C3 + n] : 0.0f;  // K,N zero-pad
                w3f[t*8 + jj] = (_Float16)w3v;
            }
            b2f[t] = b2[n];
            b3f[t] = (n < C3) ? b3[n] : 0.0f;
        }
        return;
    }
    int t = blockIdx.x * 256 + threadIdx.x;    // NVIEW*HF*WF = 131072 threads
    int pix = t & (PLANE - 1);
    int v = t >> 14;
    const float* fp = feats + ((size_t)v * CIN) * PLANE + pix;
    float f[CIN];
#pragma unroll
    for (int c = 0; c < CIN; c++) f[c] = fp[(size_t)c * PLANE];
    float g[C1];
#pragma unroll
    for (int jj = 0; jj < C1; jj++) g[jj] = b1[jj];
#pragma unroll
    for (int c = 0; c < CIN; c++) {
        float fc = f[c];
#pragma unroll
        for (int jj = 0; jj < C1; jj++) g[jj] = fmaf(fc, W1[c*C1 + jj], g[jj]);
    }
#pragma unroll
    for (int q = 0; q < C1/4; q++)
        G4[((size_t)(v * 8 + q)) * PLANE + pix] =
            make_float4(g[4*q], g[4*q+1], g[4*q+2], g[4*q+3]);
}

// ---- K2: 1 wave per 64-voxel column. Lane (m,g): blends ch 8g..8g+7 of point
// T*16+m directly into the MFMA A-frag (no h1 LDS). msum via ballot popcount. ----
__global__ void __launch_bounds__(64) k_main(
    const float4* __restrict__ G4,
    const float* __restrict__ mats, const float* __restrict__ bbox,
    const _Float16* __restrict__ w2f, const _Float16* __restrict__ w3f,
    const float* __restrict__ b2f, const float* __restrict__ b3f,
    float* __restrict__ out) {
    __shared__ __align__(16) _Float16 h2h[64 * 24];   // [point][ch], stride 24 halves (48 B)

    int lane = threadIdx.x;
    int bid  = blockIdx.x;                 // 4096 blocks: (k<<6)|j
    int j = bid & 63;
    int k = bid >> 6;
    int m = lane & 15, g = lane >> 4;
    float y = vox_coord(j, bbox[1]);
    float z = vox_coord(k, bbox[2]);

    half8_t w2frag = *(const half8_t*)(w2f + lane * 8);
    half8_t w3frag = *(const half8_t*)(w3f + lane * 8);
    float b2c = b2f[lane];
    float b3c = b3f[lane];
    floatx4 zf4 = {0.0f, 0.0f, 0.0f, 0.0f};

    float M1[16], Msq[16], S16[16];
#pragma unroll
    for (int c = 0; c < 16; c++) { M1[c] = 0.0f; Msq[c] = 0.0f; S16[c] = 0.0f; }

#pragma unroll 1
    for (int v = 0; v < NVIEW; v++) {
        const float* M = mats + v * 12;
        const float4* Gv = G4 + (size_t)v * 8 * PLANE;

        floatx4 c2v[4];
        unsigned int ballo[4];
        int popc = 0;

#pragma unroll
        for (int T = 0; T < 4; T++) {
            int ipt = T * 16 + m;                      // point index in column
            float x = vox_coord(ipt, bbox[0]);
            float ix, iy, zc;
            proj_ixiy(M, x, y, z, ix, iy, zc);

            float fx0 = floorf(ix), fy0 = floorf(iy);
            float fx1 = fx0 + 1.0f, fy1 = fy0 + 1.0f;
            bool inb = (ix >= 0.0f) && (ix <= (float)(WF-1)) &&
                       (iy >= 0.0f) && (iy <= (float)(HF-1)) && (zc > 0.0f);
            int cx0 = (int)fminf(fmaxf(fx0, 0.0f), (float)(WF-1));
            int cx1 = (int)fminf(fmaxf(fx1, 0.0f), (float)(WF-1));
            int cy0 = (int)fminf(fmaxf(fy0, 0.0f), (float)(HF-1));
            int cy1 = (int)fminf(fmaxf(fy1, 0.0f), (float)(HF-1));
            float wnw = (fx1 - ix) * (fy1 - iy);
            float wne = (ix - fx0) * (fy1 - iy);
            float wsw = (fx1 - ix) * (iy - fy0);
            float wse = (ix - fx0) * (iy - fy0);

            unsigned long long bal = __ballot(inb);    // 4 identical copies per point
            ballo[T] = (unsigned int)bal;              // bits 0..15 = g-group 0
            popc += __popcll(bal);

            int t00 = cy0 * WF + cx0, t01 = cy0 * WF + cx1;
            int t10 = cy1 * WF + cx0, t11 = cy1 * WF + cx1;
            const float4* P0 = Gv + (2*g)     * PLANE;
            const float4* P1 = Gv + (2*g + 1) * PLANE;
            float4 a0 = P0[t00], b0 = P0[t01], c0 = P0[t10], d0 = P0[t11];
            float4 a1 = P1[t00], b1v = P1[t01], c1 = P1[t10], d1 = P1[t11];

            float e0 = fmaxf(fmaf(wnw, a0.x, fmaf(wne, b0.x, fmaf(wsw, c0.x, wse * d0.x))), 0.0f);
            float e1 = fmaxf(fmaf(wnw, a0.y, fmaf(wne, b0.y, fmaf(wsw, c0.y, wse * d0.y))), 0.0f);
            float e2 = fmaxf(fmaf(wnw, a0.z, fmaf(wne, b0.z, fmaf(wsw, c0.z, wse * d0.z))), 0.0f);
            float e3 = fmaxf(fmaf(wnw, a0.w, fmaf(wne, b0.w, fmaf(wsw, c0.w, wse * d0.w))), 0.0f);
            float e4 = fmaxf(fmaf(wnw, a1.x, fmaf(wne, b1v.x, fmaf(wsw, c1.x, wse * d1.x))), 0.0f);
            float e5 = fmaxf(fmaf(wnw, a1.y, fmaf(wne, b1v.y, fmaf(wsw, c1.y, wse * d1.y))), 0.0f);
            float e6 = fmaxf(fmaf(wnw, a1.z, fmaf(wne, b1v.z, fmaf(wsw, c1.z, wse * d1.z))), 0.0f);
            float e7 = fmaxf(fmaf(wnw, a1.w, fmaf(wne, b1v.w, fmaf(wsw, c1.w, wse * d1.w))), 0.0f);

            union { half8_t h8; half2_t h2[4]; } u;
            u.h2[0] = __builtin_bit_cast(half2_t, __builtin_amdgcn_cvt_pkrtz(e0, e1));
            u.h2[1] = __builtin_bit_cast(half2_t, __builtin_amdgcn_cvt_pkrtz(e2, e3));
            u.h2[2] = __builtin_bit_cast(half2_t, __builtin_amdgcn_cvt_pkrtz(e4, e5));
            u.h2[3] = __builtin_bit_cast(half2_t, __builtin_amdgcn_cvt_pkrtz(e6, e7));

            c2v[T] = __builtin_amdgcn_mfma_f32_16x16x32_f16(u.h8, w2frag, zf4, 0, 0, 0);
        }

        // bias + relu in C-layout (lane&15 = out-channel n), store h2 [pt][ch]
        wave_lds_sync();   // guard WAR vs previous view's h2 reads (cheap)
#pragma unroll
        for (int T = 0; T < 4; T++) {
#pragma unroll
            for (int r = 0; r < 4; r++) {
                float vv = fmaxf(c2v[T][r] + b2c, 0.0f);
                h2h[(T*16 + g*4 + r) * 24 + m] = (_Float16)vv;
            }
        }
        wave_lds_sync();

        // layer 3: A = h2 rows (lane&15 = point-row), B = zero-padded W3
        float msr = __builtin_amdgcn_rcpf((float)(popc >> 2) + 1e-8f);
#pragma unroll
        for (int T = 0; T < 4; T++) {
            half8_t a3 = *(const half8_t*)(h2h + (T*16 + m) * 24 + (g & 1) * 8);
            floatx4 c3 = __builtin_amdgcn_mfma_f32_16x16x32_f16(a3, w3frag, zf4, 0, 0, 0);
#pragma unroll
            for (int r = 0; r < 4; r++) {
                float w = ((ballo[T] >> (g*4 + r)) & 1u) ? msr : 0.0f;
                float val = c3[r] + b3c;
                float t1 = w * val;
                S16[T*4+r] += w;
                M1[T*4+r]  += t1;
                Msq[T*4+r]  = fmaf(t1, val, Msq[T*4+r]);
            }
        }
    }

    // epilogue: lane (m<8, g) stores points T*16+g*4..+3, mean plane m, var plane m+8
    if (m < C3) {
        size_t base = (size_t)bid * 64;
#pragma unroll
        for (int T = 0; T < 4; T++) {
            float4 mn, vr;
            mn.x = M1[T*4+0]; mn.y = M1[T*4+1]; mn.z = M1[T*4+2]; mn.w = M1[T*4+3];
            vr.x = fmaf(mn.x*mn.x, S16[T*4+0]-2.0f, Msq[T*4+0]);
            vr.y = fmaf(mn.y*mn.y, S16[T*4+1]-2.0f, Msq[T*4+1]);
            vr.z = fmaf(mn.z*mn.z, S16[T*4+2]-2.0f, Msq[T*4+2]);
            vr.w = fmaf(mn.w*mn.w, S16[T*4+3]-2.0f, Msq[T*4+3]);
            size_t ob = base + T*16 + g*4;
            *(float4*)(out + (size_t)m       * 262144 + ob) = mn;
            *(float4*)(out + (size_t)(m + 8) * 262144 + ob) = vr;
        }
    }
}

// ---- launch ----
extern "C" void kernel_launch(void* const* d_in, const int* in_sizes, int n_in,
                              void* d_out, int out_size, void* d_ws, size_t ws_size,
                              hipStream_t stream) {
    const float* feats = (const float*)d_in[0];
    const float* poses = (const float*)d_in[1];
    const float* Ks    = (const float*)d_in[2];
    const float* bbox  = (const float*)d_in[3];
    const int*   img_h = (const int*)d_in[4];
    const int*   img_w = (const int*)d_in[5];
    const float* W1    = (const float*)d_in[6];
    const float* b1    = (const float*)d_in[7];
    const float* W2    = (const float*)d_in[8];
    const float* b2    = (const float*)d_in[9];
    const float* W3    = (const float*)d_in[10];
    const float* b3    = (const float*)d_in[11];
    float* out = (float*)d_out;
    float* ws  = (float*)d_ws;

    float*     mats = ws;                        // 96 floats (pad to 128)
    _Float16*  w2f  = (_Float16*)(ws + 128);     // 512 halves (256 floats)
    _Float16*  w3f  = (_Float16*)(ws + 384);     // 512 halves
    float*     b2f  = ws + 640;                  // 64
    float*     b3f  = ws + 704;                  // 64
    float4*    G4   = (float4*)(ws + 768);       // 8*8*16384 float4 = 16 MB, 16B-aligned

    hipLaunchKernelGGL(k_g, dim3(513), dim3(256), 0, stream,
                       feats, W1, b1, G4, Ks, poses, img_h, img_w,
                       W2, b2, W3, b3, mats, w2f, w3f, b2f, b3f);
    hipLaunchKernelGGL(k_main, dim3(4096), dim3(64), 0, stream,
                       G4, mats, bbox, w2f, w3f, b2f, b3f, out);
}